// Round 10
// baseline (537.404 us; speedup 1.0000x reference)
//
#include <hip/hip_runtime.h>
#include <hip/hip_bf16.h>

// TimeMoERouter: B=8 S=512 H=1024 E=8 TOPK=2 NHEADS=8 DH=128 CAP=1536
// Round 10: r9 (8 waves/block, 128x128 tile, 4 waves/SIMD) with the EPI==0
// epilogue store-loop coverage bug fixed (was writing half the tile).

#define Hh 1024

typedef __attribute__((ext_vector_type(8))) short short8v;
typedef __attribute__((ext_vector_type(4))) float f32x4;

static __device__ __forceinline__ ushort f2bf(float x) {
  uint u = __float_as_uint(x);
  u += 0x7FFF + ((u >> 16) & 1);          // round-to-nearest-even
  return (ushort)(u >> 16);
}
static __device__ __forceinline__ float bf2f(ushort h) {
  return __uint_as_float(((uint)h) << 16);
}

// ---------------- split-precision MFMA GEMM ----------------
// C[m,n] = alpha * sum_k A[m,k]*B[n,k], segments (Ah,Bh)+(Al,Bh)+(Ah,Bl).
// A: bf16, row stride lda, hi col aHi+k, lo col aLo+k (LDS-staged, dbuf).
// Bf: frag-native [hl][BNT][BKC][64][8].
// EPI: 0 fp32 C; 1 split bf16 row-major (hi col n, lo col n+splitOff);
//      2 QKV: n0<1024 -> Q split row-major; <2048 -> Kf frags; else Vf.
// Tile 128x128, BK=32, 8 waves (2x4), wave tile 64x32, 16x16x32 bf16 MFMA.
template<int EPI, bool RELU, bool HAS_BN, bool HAS_BSN>
__global__ __launch_bounds__(512, 4) void mgemm_k(
    const ushort* __restrict__ A, int lda, long long sAmaj, long long sAmin, int aHi, int aLo,
    const ushort* __restrict__ Bf, int BNT, int BKC, long long sBmaj, long long sBmin,
    float* __restrict__ Cf, ushort* __restrict__ Ch, int ldc, long long sCmaj, long long sCmin,
    int splitOff,
    ushort* __restrict__ pK, ushort* __restrict__ pV,
    int Kd, int zdiv,
    const float* __restrict__ bN, const float* __restrict__ bSN, int ldbs, int smod,
    float alpha)
{
  // XCD-aware bijective swizzle (all grids are multiples of 8)
  int gx = gridDim.x, gy = gridDim.y;
  int lin = (blockIdx.z * gy + blockIdx.y) * gx + blockIdx.x;
  int nwg = gx * gy * gridDim.z;
  int cpx = nwg >> 3;
  int swz = (lin & 7) * cpx + (lin >> 3);
  int bz = swz / (gx * gy);
  int rem = swz - bz * (gx * gy);
  int by = rem / gx, bx = rem - by * gx;

  int zj = bz / zdiv, zi = bz - zj * zdiv;
  A += (size_t)zj * sAmaj + (size_t)zi * sAmin;
  const ushort* bfb = Bf + (size_t)zj * sBmaj + (size_t)zi * sBmin;
  long long coff = (long long)zj * sCmaj + (long long)zi * sCmin;

  int m0 = by * 128, n0 = bx * 128;

  __shared__ __align__(16) ushort smem[16384];   // 32KB: 2 bufs x {Ah 8K, Al 8K}

  int t = threadIdx.x;
  int l = t & 63, w = t >> 6;       // 8 waves
  int wm = w >> 2, wn = w & 3;      // 2 x 4

  f32x4 acc[4][2];
#pragma unroll
  for (int i = 0; i < 4; ++i)
#pragma unroll
    for (int j = 0; j < 2; ++j) acc[i][j] = (f32x4){0.f, 0.f, 0.f, 0.f};

  // A staging: thread covers row srow (0..127), int4-slot sc (0..3)
  int srow = t >> 2;
  int sc = t & 3;
  const ushort* gAh = A + (size_t)(m0 + srow) * lda + aHi + sc * 8;
  const ushort* gAl = A + (size_t)(m0 + srow) * lda + aLo + sc * 8;
  int wo = (srow * 64 + sc * 16) ^ (((srow >> 1) & 7) << 4);

  // A fragment read offsets (wave rows: wm*64 + mi*16)
  int aoff[4];
#pragma unroll
  for (int mi = 0; mi < 4; ++mi) {
    int row = wm * 64 + mi * 16 + (l & 15);
    aoff[mi] = (row * 64 + (l >> 4) * 16) ^ (((row >> 1) & 7) << 4);
  }

  // B frag pointers (2 nt per wave, hi and lo)
  const ushort* bph[2];
  const ushort* bpl[2];
  int ntg0 = (n0 >> 4) + wn * 2;
#pragma unroll
  for (int ni = 0; ni < 2; ++ni) {
    bph[ni] = bfb + ((size_t)(ntg0 + ni) * BKC) * 512 + l * 8;
    bpl[ni] = bfb + ((size_t)(BNT + ntg0 + ni) * BKC) * 512 + l * 8;
  }

  int4 a0h, a0l, a1h, a1l;
  short8v B0h[2], B0l[2], B1h[2], B1l[2];

#define LOADA0(s) { a0h = *(const int4*)(gAh + (s)*32); a0l = *(const int4*)(gAl + (s)*32); }
#define LOADA1(s) { a1h = *(const int4*)(gAh + (s)*32); a1l = *(const int4*)(gAl + (s)*32); }
#define STOREA(h, lo2, base) { char* nb = (char*)smem + (base); \
    *(int4*)(nb + wo) = h; *(int4*)(nb + 8192 + wo) = lo2; }
#define LOADB(BH, BL, s) { _Pragma("unroll") \
    for (int ni = 0; ni < 2; ++ni) { \
      BH[ni] = *(const short8v*)(bph[ni] + (size_t)(s) * 512); \
      BL[ni] = *(const short8v*)(bpl[ni] + (size_t)(s) * 512); } }
#define MFMA_STEP(ahb, alb, BH, BL) { \
    short8v ah[4], al[4]; \
    _Pragma("unroll") for (int mi = 0; mi < 4; ++mi) \
      ah[mi] = *(const short8v*)((char*)smem + (ahb) + aoff[mi]); \
    _Pragma("unroll") for (int mi = 0; mi < 4; ++mi) \
      al[mi] = *(const short8v*)((char*)smem + (alb) + aoff[mi]); \
    _Pragma("unroll") for (int ni = 0; ni < 2; ++ni) \
      _Pragma("unroll") for (int mi = 0; mi < 4; ++mi) \
        acc[mi][ni] = __builtin_amdgcn_mfma_f32_16x16x32_bf16(ah[mi], BH[ni], acc[mi][ni], 0, 0, 0); \
    _Pragma("unroll") for (int ni = 0; ni < 2; ++ni) \
      _Pragma("unroll") for (int mi = 0; mi < 4; ++mi) \
        acc[mi][ni] = __builtin_amdgcn_mfma_f32_16x16x32_bf16(al[mi], BH[ni], acc[mi][ni], 0, 0, 0); \
    _Pragma("unroll") for (int ni = 0; ni < 2; ++ni) \
      _Pragma("unroll") for (int mi = 0; mi < 4; ++mi) \
        acc[mi][ni] = __builtin_amdgcn_mfma_f32_16x16x32_bf16(ah[mi], BL[ni], acc[mi][ni], 0, 0, 0); }

  int nt = Kd >> 5;            // always even (>=4)
  LOADA0(0); LOADB(B0h, B0l, 0);
  LOADA1(1); LOADB(B1h, B1l, 1);
  STOREA(a0h, a0l, 0);
  __syncthreads();
  for (int s2 = 0; s2 < nt; s2 += 2) {
    if (s2 + 2 < nt) LOADA0(s2 + 2);
    MFMA_STEP(0, 8192, B0h, B0l);
    if (s2 + 2 < nt) LOADB(B0h, B0l, s2 + 2);
    STOREA(a1h, a1l, 16384);
    __syncthreads();
    if (s2 + 3 < nt) LOADA1(s2 + 3);
    MFMA_STEP(16384, 24576, B1h, B1l);
    if (s2 + 3 < nt) LOADB(B1h, B1l, s2 + 3);
    if (s2 + 2 < nt) STOREA(a0h, a0l, 0);
    __syncthreads();
  }
#undef LOADA0
#undef LOADA1
#undef STOREA
#undef LOADB
#undef MFMA_STEP

  // fold alpha + biases + relu into acc
#pragma unroll
  for (int mi = 0; mi < 4; ++mi)
#pragma unroll
    for (int j = 0; j < 4; ++j) {
      int m = m0 + wm * 64 + mi * 16 + (l >> 4) * 4 + j;
#pragma unroll
      for (int ni = 0; ni < 2; ++ni) {
        int n = n0 + wn * 32 + ni * 16 + (l & 15);
        float x = acc[mi][ni][j] * alpha;
        if (HAS_BN) x += bN[n];
        if (HAS_BSN) x += bSN[(size_t)(m % smod) * ldbs + n];
        if (RELU) x = fmaxf(x, 0.f);
        acc[mi][ni][j] = x;
      }
    }

  if (EPI == 0) {
    // fp32 LDS-bounce: two 64-row passes (wm halves), coalesced int4 stores
    float* Fs = (float*)smem;
#pragma unroll
    for (int p = 0; p < 2; ++p) {
      __syncthreads();
      if (wm == p) {
#pragma unroll
        for (int mi = 0; mi < 4; ++mi)
#pragma unroll
          for (int j = 0; j < 4; ++j) {
            int r = mi * 16 + (l >> 4) * 4 + j;
#pragma unroll
            for (int ni = 0; ni < 2; ++ni) {
              int c = wn * 32 + ni * 16 + (l & 15);
              *(float*)((char*)Fs + ((r * 512 + c * 4) ^ ((r & 7) << 4))) = acc[mi][ni][j];
            }
          }
      }
      __syncthreads();
      // FIX (r9 bug): 64 rows x 32 int4-slots = 2048 int4; 4 x 512 covers it
#pragma unroll
      for (int r2 = 0; r2 < 4; ++r2) {
        int idx = r2 * 512 + t;
        int row = idx >> 5, slot = idx & 31;
        int4 v = *(const int4*)((char*)Fs + ((row * 512 + slot * 16) ^ ((row & 7) << 4)));
        *(int4*)(Cf + coff + (size_t)(m0 + p * 64 + row) * ldc + n0 + slot * 4) = v;
      }
    }
  } else {
    __syncthreads();
    ushort* Es = smem;                     // [128][128] ushort = 32KB
    bool isQ = (EPI == 1) || (n0 < 1024);
    bool isK = (EPI == 2) && !isQ && (n0 < 2048);
    int bb = m0 >> 9, s0 = m0 & 511;
    int hh2 = isK ? ((n0 - 1024) >> 7) : ((n0 - 2048) >> 7);
    size_t kvb = (size_t)(bb * 8 + hh2) * 131072;
#pragma unroll
    for (int pass = 0; pass < 2; ++pass) {
      if (!(EPI == 2 && !isQ && !isK)) {
        // row-major [128][128] ush (Q and K)
#pragma unroll
        for (int mi = 0; mi < 4; ++mi)
#pragma unroll
          for (int j = 0; j < 4; ++j) {
            int lr = wm * 64 + mi * 16 + (l >> 4) * 4 + j;
#pragma unroll
            for (int ni = 0; ni < 2; ++ni) {
              int lcb = (wn * 32 + ni * 16 + (l & 15)) * 2;
              float x = acc[mi][ni][j];
              ushort h = f2bf(x);
              ushort vv = (pass == 0) ? h : f2bf(x - bf2f(h));
              *(ushort*)((char*)Es + ((lr * 256 + lcb) ^ ((lr & 7) << 4))) = vv;
            }
          }
      } else {
        // V: transposed (rows = n-local = d, cols = m-local = s)
#pragma unroll
        for (int mi = 0; mi < 4; ++mi)
#pragma unroll
          for (int j = 0; j < 4; ++j) {
            int cc = (wm * 64 + mi * 16 + (l >> 4) * 4 + j) * 2;
#pragma unroll
            for (int ni = 0; ni < 2; ++ni) {
              int rr = wn * 32 + ni * 16 + (l & 15);
              float x = acc[mi][ni][j];
              ushort h = f2bf(x);
              ushort vv = (pass == 0) ? h : f2bf(x - bf2f(h));
              *(ushort*)((char*)Es + ((rr * 256 + cc) ^ ((rr & 7) << 4))) = vv;
            }
          }
      }
      __syncthreads();
      if (isQ) {
        int off = (pass == 0) ? 0 : splitOff;
#pragma unroll
        for (int r = 0; r < 4; ++r) {
          int idx = r * 512 + t;
          int row = idx >> 4, cb = (idx & 15) * 16;
          int4 v = *(const int4*)((char*)Es + ((row * 256 + cb) ^ ((row & 7) << 4)));
          *(int4*)((char*)(Ch + coff + (size_t)(m0 + row) * ldc + off + n0) + cb) = v;
        }
      } else if (isK) {
#pragma unroll
        for (int sw = 0; sw < 4; ++sw) {
          int idx = sw * 512 + t;
          int f = idx >> 6, l2 = idx & 63;
          int st = f >> 2, dc = f & 3;
          int row = st * 16 + (l2 & 15);
          int colB = (dc * 32 + ((l2 >> 4) << 3)) * 2;
          short8v v = *(const short8v*)((char*)Es + ((row * 256 + colB) ^ ((row & 7) << 4)));
          *(short8v*)(pK + kvb + (size_t)((pass * 32 + (s0 >> 4) + st) * 4 + dc) * 512 + l2 * 8) = v;
        }
      } else {
#pragma unroll
        for (int sw = 0; sw < 4; ++sw) {
          int idx = sw * 512 + t;
          int f = idx >> 6, l2 = idx & 63;
          int dt = f >> 2, sch = f & 3;
          int row = dt * 16 + (l2 & 15);
          int colB = (sch * 32 + ((l2 >> 4) << 3)) * 2;
          short8v v = *(const short8v*)((char*)Es + ((row * 256 + colB) ^ ((row & 7) << 4)));
          *(short8v*)(pV + kvb + (size_t)((pass * 8 + dt) * 16 + (s0 >> 5) + sch) * 512 + l2 * 8) = v;
        }
      }
      if (pass == 0) __syncthreads();
    }
  }
}

// ------- merged fp32 [N][K] -> frag-native hi|lo for all 5 weights -------
__global__ __launch_bounds__(64) void convall_k(
    const float* __restrict__ te_w1, const float* __restrict__ te_w2,
    const float* __restrict__ ain_w, const float* __restrict__ aout_w,
    const float* __restrict__ tr_w1, ushort* __restrict__ base)
{
  int kc = blockIdx.x, y = blockIdx.y, l = threadIdx.x;
  const float* W; int ldw, NT, nt2; ushort* dst;
  if (y < 64)       { W = te_w1;  ldw = 1026; NT = 64;  nt2 = y;       dst = base; }
  else if (y < 128) { W = te_w2;  ldw = 1024; NT = 64;  nt2 = y - 64;  dst = base + 2097152; }
  else if (y < 320) { W = ain_w;  ldw = 1024; NT = 192; nt2 = y - 128; dst = base + 4194304; }
  else if (y < 384) { W = aout_w; ldw = 1024; NT = 64;  nt2 = y - 320; dst = base + 10485760; }
  else              { W = tr_w1;  ldw = 1024; NT = 64;  nt2 = y - 384; dst = base + 12582912; }
  const float* src = W + (size_t)(nt2 * 16 + (l & 15)) * ldw + kc * 32 + ((l >> 4) << 3);
  ushort h8[8], l8[8];
#pragma unroll
  for (int j = 0; j < 8; ++j) {
    float x = src[j];
    h8[j] = f2bf(x);
    l8[j] = f2bf(x - bf2f(h8[j]));
  }
  *(int4*)(dst + ((size_t)nt2 * 32 + kc) * 512 + l * 8) = *(int4*)h8;
  *(int4*)(dst + ((size_t)(NT + nt2) * 32 + kc) * 512 + l * 8) = *(int4*)l8;
}

// ---------------- fp32 [N][K] -> bf16 hi|lo [N][2K] (row-major, for A) ----
__global__ __launch_bounds__(256) void convert_k(
    const float* __restrict__ W, int lda, ushort* __restrict__ Whl, int K)
{
  int r = blockIdx.x;
  int c = threadIdx.x * 4;
  const float* src = W + (size_t)r * lda + c;
  float x0 = src[0], x1 = src[1], x2 = src[2], x3 = src[3];
  ushort4 h, lo;
  h.x = f2bf(x0); lo.x = f2bf(x0 - bf2f(h.x));
  h.y = f2bf(x1); lo.y = f2bf(x1 - bf2f(h.y));
  h.z = f2bf(x2); lo.z = f2bf(x2 - bf2f(h.z));
  h.w = f2bf(x3); lo.w = f2bf(x3 - bf2f(h.w));
  ushort* dst = Whl + (size_t)r * 2 * K;
  *(ushort4*)&dst[c] = h;
  *(ushort4*)&dst[K + c] = lo;
}

// ---------------- seasonal / positional precompute (fp32) ----------------
__global__ __launch_bounds__(256) void precompute_k(
    const float* __restrict__ pos_emb,
    const float* __restrict__ se_w1, const float* __restrict__ se_b1,
    const float* __restrict__ se_w2, const float* __restrict__ se_b2,
    const float* __restrict__ sexp_w, const float* __restrict__ sexp_b,
    const float* __restrict__ te_w1, const float* __restrict__ te_b1,
    float* __restrict__ psea, float* __restrict__ bias1)
{
  int s = blockIdx.x, t = threadIdx.x;
  float ts = (float)s;
  float se = sinf(((ts * 2.0f) * 3.14159274101257324f) / 24.0f);
  __shared__ float l1[256], l2[256];
  l1[t] = fmaxf(se * se_w1[t] + se_b1[t], 0.f);
  __syncthreads();
  {
    float a = se_b2[t];
    const float* wr = se_w2 + (size_t)t * 256;
    for (int i = 0; i < 256; ++i) a += l1[i] * wr[i];
    l2[t] = a;
  }
  __syncthreads();
#pragma unroll
  for (int r = 0; r < 4; ++r) {
    int h = r * 256 + t;
    float v = sexp_b[h];
    const float* wr = sexp_w + (size_t)h * 256;
    for (int j = 0; j < 256; ++j) v += l2[j] * wr[j];
    psea[s * Hh + h] = pos_emb[s * Hh + h] + v;
    bias1[s * Hh + h] = te_b1[h] + ts * te_w1[(size_t)h * 1026 + 1024]
                                 + se * te_w1[(size_t)h * 1026 + 1025];
  }
}

// ---------------- softmax over score rows; writes split P in place --------
__global__ __launch_bounds__(256) void softmax2_k(float* __restrict__ S)
{
  int row = blockIdx.x * 4 + (threadIdx.x >> 6);
  int lane = threadIdx.x & 63;
  float* p = S + (size_t)row * 512;
  float4 a = *(float4*)&p[lane * 4];
  float4 b = *(float4*)&p[256 + lane * 4];
  float m = fmaxf(fmaxf(fmaxf(a.x, a.y), fmaxf(a.z, a.w)),
                  fmaxf(fmaxf(b.x, b.y), fmaxf(b.z, b.w)));
#pragma unroll
  for (int off = 32; off; off >>= 1) m = fmaxf(m, __shfl_xor(m, off));
  a.x = expf(a.x - m); a.y = expf(a.y - m); a.z = expf(a.z - m); a.w = expf(a.w - m);
  b.x = expf(b.x - m); b.y = expf(b.y - m); b.z = expf(b.z - m); b.w = expf(b.w - m);
  float s = a.x + a.y + a.z + a.w + b.x + b.y + b.z + b.w;
#pragma unroll
  for (int off = 32; off; off >>= 1) s += __shfl_xor(s, off);
  float inv = 1.f / s;
  a.x *= inv; a.y *= inv; a.z *= inv; a.w *= inv;
  b.x *= inv; b.y *= inv; b.z *= inv; b.w *= inv;
  ushort* u = (ushort*)S + (size_t)row * 1024;    // [hi 512 | lo 512]
  ushort4 ha, la, hb, lb;
  ha.x = f2bf(a.x); la.x = f2bf(a.x - bf2f(ha.x));
  ha.y = f2bf(a.y); la.y = f2bf(a.y - bf2f(ha.y));
  ha.z = f2bf(a.z); la.z = f2bf(a.z - bf2f(ha.z));
  ha.w = f2bf(a.w); la.w = f2bf(a.w - bf2f(ha.w));
  hb.x = f2bf(b.x); lb.x = f2bf(b.x - bf2f(hb.x));
  hb.y = f2bf(b.y); lb.y = f2bf(b.y - bf2f(hb.y));
  hb.z = f2bf(b.z); lb.z = f2bf(b.z - bf2f(hb.z));
  hb.w = f2bf(b.w); lb.w = f2bf(b.w - bf2f(hb.w));
  *(ushort4*)&u[lane * 4] = ha;
  *(ushort4*)&u[512 + lane * 4] = la;
  *(ushort4*)&u[256 + lane * 4] = hb;
  *(ushort4*)&u[768 + lane * 4] = lb;
}

// ---------------- logits = h1 @ tr_w2^T + b  (N=8, fp32 VALU) ----------
__global__ __launch_bounds__(256) void tr2_k(
    const float* __restrict__ h1, const float* __restrict__ w,
    const float* __restrict__ bias, float* __restrict__ logits)
{
  int wid = threadIdx.x >> 6, lane = threadIdx.x & 63;
  int t = blockIdx.x * 4 + wid;
  const float* x = h1 + (size_t)t * Hh;
  float acc[8];
#pragma unroll
  for (int e = 0; e < 8; ++e) acc[e] = 0.f;
  for (int k = lane; k < Hh; k += 64) {
    float xv = x[k];
#pragma unroll
    for (int e = 0; e < 8; ++e) acc[e] += xv * w[e * Hh + k];
  }
#pragma unroll
  for (int e = 0; e < 8; ++e) {
#pragma unroll
    for (int off = 32; off; off >>= 1) acc[e] += __shfl_xor(acc[e], off);
  }
  if (lane == 0) {
#pragma unroll
    for (int e = 0; e < 8; ++e) logits[(size_t)t * 8 + e] = acc[e] + bias[e];
  }
}

// ---------------- zero fill of dispatch+combine ----------------
__global__ __launch_bounds__(256) void fill0_k(float4* __restrict__ p, long long n4)
{
  long long i = (long long)blockIdx.x * 256 + threadIdx.x;
  long long stride = (long long)gridDim.x * 256;
  float4 z = make_float4(0.f, 0.f, 0.f, 0.f);
  for (; i < n4; i += stride) p[i] = z;
}

// ---------------- router: softmax, top2, slot writes, partial p-sums -------
__global__ __launch_bounds__(256) void router_k(
    float* __restrict__ out, float* __restrict__ partials)
{
  int t = blockIdx.x * 256 + threadIdx.x;            // token 0..4095
  float* lg = out + 100663296 + (size_t)t * 8;       // logits (in-place -> probs)
  float p[8];
#pragma unroll
  for (int e = 0; e < 8; ++e) p[e] = lg[e];
  float m = p[0];
#pragma unroll
  for (int e = 1; e < 8; ++e) m = fmaxf(m, p[e]);
  float s = 0.f;
#pragma unroll
  for (int e = 0; e < 8; ++e) { p[e] = expf(p[e] - m); s += p[e]; }
  float inv = 1.f / s;
#pragma unroll
  for (int e = 0; e < 8; ++e) p[e] *= inv;
#pragma unroll
  for (int e = 0; e < 8; ++e) lg[e] = p[e];          // router_probs out

  int i0 = 0; float v0 = p[0];
#pragma unroll
  for (int e = 1; e < 8; ++e) if (p[e] > v0) { v0 = p[e]; i0 = e; }
  int i1 = -1; float v1 = -1.f;
#pragma unroll
  for (int e = 0; e < 8; ++e) if (e != i0 && p[e] > v1) { v1 = p[e]; i1 = e; }
  float wn = 1.f / (v0 + v1);
  size_t db = (size_t)t * (8 * 1536);
  out[db + (size_t)i0 * 1536] = 1.f;
  out[db + (size_t)i1 * 1536] = 1.f;
  out[50331648 + db + (size_t)i0 * 1536] = v0 * wn;
  out[50331648 + db + (size_t)i1 * 1536] = v1 * wn;

  __shared__ float red[256];
#pragma unroll
  for (int e = 0; e < 8; ++e) {
    red[threadIdx.x] = p[e];
    __syncthreads();
    for (int st = 128; st; st >>= 1) {
      if (threadIdx.x < st) red[threadIdx.x] += red[threadIdx.x + st];
      __syncthreads();
    }
    if (threadIdx.x == 0) partials[blockIdx.x * 8 + e] = red[0];
    __syncthreads();
  }
}

// ---------------- aux loss + cleanup of partials scratch ----------------
__global__ __launch_bounds__(64) void aux_k(float* __restrict__ partials,
                                            float* __restrict__ out)
{
  int lane = threadIdx.x;
  float v = 0.f;
  if (lane < 8) {
    float s = 0.f;
    for (int b = 0; b < 16; ++b) s += partials[b * 8 + lane];
    float pm = s / 4096.f;
    v = pm * logf(pm * 8.f + 1e-9f);
  }
#pragma unroll
  for (int off = 4; off; off >>= 1) v += __shfl_xor(v, off);
  if (lane == 0) out[100696064] = v;
  partials[lane] = 0.f;
  partials[64 + lane] = 0.f;
}

extern "C" void kernel_launch(void* const* d_in, const int* in_sizes, int n_in,
                              void* d_out, int out_size, void* d_ws, size_t ws_size,
                              hipStream_t stream)
{
  const float* hidden = (const float*)d_in[0];
  const float* pos_emb = (const float*)d_in[1];
  const float* se_w1 = (const float*)d_in[2];
  const float* se_b1 = (const float*)d_in[3];
  const float* se_w2 = (const float*)d_in[4];
  const float* se_b2 = (const float*)d_in[5];
  const float* sexp_w = (const float*)d_in[6];
  const float* sexp_b = (const float*)d_in[7];
  const float* te_w1 = (const float*)d_in[8];
  const float* te_b1 = (const float*)d_in[9];
  const float* te_w2 = (const float*)d_in[10];
  const float* te_b2 = (const float*)d_in[11];
  const float* ain_w = (const float*)d_in[12];
  const float* ain_b = (const float*)d_in[13];
  const float* aout_w = (const float*)d_in[14];
  const float* aout_b = (const float*)d_in[15];
  const float* tr_w1 = (const float*)d_in[16];
  const float* tr_b1 = (const float*)d_in[17];
  const float* tr_w2 = (const float*)d_in[18];
  const float* tr_b2 = (const float*)d_in[19];
  float* out = (float*)d_out;

  // scratch arena: byte offsets inside d_out's dispatch+combine region (402MB)
  char* arena = (char*)d_out;
  ushort* Wbase= (ushort*)(arena + 0);          // W1f/W2f/Waf/Wof/Wtf 28MB
  ushort* hid2 = (ushort*)(arena + 29360128);   // [4096][2048] 16MB
  ushort* enc1 = (ushort*)(arena + 46137344);   // 16MB
  ushort* enc2 = (ushort*)(arena + 62914560);   // 16MB
  ushort* qbuf = (ushort*)(arena + 79691776);   // [4096][2048] 16MB
  ushort* Kf   = (ushort*)(arena + 96468992);   // [64][2][32][4][512] 16MB
  ushort* Vf   = (ushort*)(arena + 113246208);  // [64][2][8][16][512] 16MB
  float*  scor = (float*)(arena + 130023424);   // [64][512][512] 64MB -> split P
  ushort* attno= (ushort*)(arena + 197132288);  // 16MB
  ushort* encf = (ushort*)(arena + 213909504);  // 16MB
  float*  h1   = (float*)(arena + 230686720);   // [4096][1024] 16MB
  float*  psea = (float*)(arena + 247463936);   // 2MB
  float*  bias1= (float*)(arena + 249561088);   // 2MB
  float*  parts= out + 51380224;                // [16][8], zeroed by aux_k
  float*  lgts = out + 100663296;               // logits -> probs region

  // weight / input expansions
  convall_k<<<dim3(32, 448), 64, 0, stream>>>(te_w1, te_w2, ain_w, aout_w, tr_w1, Wbase);
  convert_k<<<4096, 256, 0, stream>>>(hidden, 1024, hid2, 1024);
  precompute_k<<<512, 256, 0, stream>>>(pos_emb, se_w1, se_b1, se_w2, se_b2,
                                        sexp_w, sexp_b, te_w1, te_b1, psea, bias1);

  // G1: enc1 = relu(hidden @ te_w1'^T + bias1[s])
  mgemm_k<1, true, false, true><<<dim3(8, 32, 1), 512, 0, stream>>>(
      hid2, 2048, 0, 0, 0, 1024,
      Wbase, 64, 32, 0, 0,
      nullptr, enc1, 2048, 0, 0, 1024, nullptr, nullptr,
      1024, 1, nullptr, bias1, 1024, 512, 1.f);

  // G2: enc2 = enc1 @ te_w2^T + te_b2 + psea[s]
  mgemm_k<1, false, true, true><<<dim3(8, 32, 1), 512, 0, stream>>>(
      enc1, 2048, 0, 0, 0, 1024,
      Wbase + 2097152, 64, 32, 0, 0,
      nullptr, enc2, 2048, 0, 0, 1024, nullptr, nullptr,
      1024, 1, te_b2, psea, 1024, 512, 1.f);

  // G3: qkv = enc2 @ attn_in_w^T + attn_in_b; Q row-major, K/V frag-native
  mgemm_k<2, false, true, false><<<dim3(24, 32, 1), 512, 0, stream>>>(
      enc2, 2048, 0, 0, 0, 1024,
      Wbase + 4194304, 192, 32, 0, 0,
      nullptr, qbuf, 2048, 0, 0, 1024, Kf, Vf,
      1024, 1, ain_b, nullptr, 1, 1, 1.f);

  // G4: scores[b,h] = Q K^T / sqrt(128)  (fp32 out)
  mgemm_k<0, false, false, false><<<dim3(4, 4, 64), 512, 0, stream>>>(
      qbuf, 2048, 1048576, 128, 0, 1024,
      Kf, 32, 4, 1048576, 131072,
      scor, nullptr, 512, 2097152, 262144, 0, nullptr, nullptr,
      128, 8, nullptr, nullptr, 1, 1, 0.08838834764831845f);

  softmax2_k<<<8192, 256, 0, stream>>>(scor);

  // G5: attno[b,h] = P @ V  (A = split P, B = Vf frag-native)
  mgemm_k<1, false, false, false><<<dim3(1, 4, 64), 512, 0, stream>>>(
      (const ushort*)scor, 1024, 4194304, 524288, 0, 512,
      Vf, 8, 16, 1048576, 131072,
      nullptr, attno, 2048, 1048576, 128, 1024, nullptr, nullptr,
      512, 8, nullptr, nullptr, 1, 1, 1.f);

  // G6: encf = attno @ attn_out_w^T + attn_out_b
  mgemm_k<1, false, true, false><<<dim3(8, 32, 1), 512, 0, stream>>>(
      attno, 2048, 0, 0, 0, 1024,
      Wbase + 10485760, 64, 32, 0, 0,
      nullptr, encf, 2048, 0, 0, 1024, nullptr, nullptr,
      1024, 1, aout_b, nullptr, 1, 1, 1.f);

  // G7: h1 = relu(encf @ tr_w1^T + tr_b1)  (fp32 out)
  mgemm_k<0, true, true, false><<<dim3(8, 32, 1), 512, 0, stream>>>(
      encf, 2048, 0, 0, 0, 1024,
      Wbase + 12582912, 64, 32, 0, 0,
      h1, nullptr, 1024, 0, 0, 0, nullptr, nullptr,
      1024, 1, tr_b1, nullptr, 1, 1, 1.f);

  tr2_k<<<1024, 256, 0, stream>>>(h1, tr_w2, tr_b2, lgts);

  // zero dispatch+combine (wipes all arena scratch)
  fill0_k<<<4096, 256, 0, stream>>>((float4*)out, 25165824LL);

  router_k<<<16, 256, 0, stream>>>(out, parts);
  aux_k<<<1, 64, 0, stream>>>(parts, out);
}

// Round 12
// 459.550 us; speedup vs baseline: 1.1694x; 1.1694x over previous
//
#include <hip/hip_runtime.h>
#include <hip/hip_bf16.h>

// TimeMoERouter: B=8 S=512 H=1024 E=8 TOPK=2 NHEADS=8 DH=128 CAP=1536
// Round 12: round 11's fused attention, with mgemm_k restored VERBATIM from
// round 5 (r11 regression: A-staging dropped odd int4 slots + wrong Al base).

#define Hh 1024

typedef __attribute__((ext_vector_type(8))) short short8v;
typedef __attribute__((ext_vector_type(4))) float f32x4;

static __device__ __forceinline__ ushort f2bf(float x) {
  uint u = __float_as_uint(x);
  u += 0x7FFF + ((u >> 16) & 1);          // round-to-nearest-even
  return (ushort)(u >> 16);
}
static __device__ __forceinline__ float bf2f(ushort h) {
  return __uint_as_float(((uint)h) << 16);
}

// ---------------- split-precision MFMA GEMM (round-5 verbatim) ----------------
// C[m,n] = alpha * sum_k A[m,k]*B[n,k], segments (Ah,Bh)+(Al,Bh)+(Ah,Bl).
// A: bf16, row stride lda, hi col aHi+k, lo col aLo+k (LDS-staged, dbuf).
// Bf: frag-native [hl][BNT][BKC][64][8].
// EPI: 0 fp32 C; 1 split bf16 row-major (hi col n, lo col n+splitOff);
//      2 QKV: n0<1024 -> Q split row-major; <2048 -> Kf frags; else Vf.
// Tile 128x128, BK=32, 4 waves (2x2), 16x16x32 bf16 MFMA.
template<int EPI, bool RELU, bool HAS_BN, bool HAS_BSN>
__global__ __launch_bounds__(256, 2) void mgemm_k(
    const ushort* __restrict__ A, int lda, long long sAmaj, long long sAmin, int aHi, int aLo,
    const ushort* __restrict__ Bf, int BNT, int BKC, long long sBmaj, long long sBmin,
    float* __restrict__ Cf, ushort* __restrict__ Ch, int ldc, long long sCmaj, long long sCmin,
    int splitOff,
    ushort* __restrict__ pK, ushort* __restrict__ pV,
    int Kd, int zdiv,
    const float* __restrict__ bN, const float* __restrict__ bSN, int ldbs, int smod,
    float alpha)
{
  // XCD-aware bijective swizzle (all grids are multiples of 8)
  int gx = gridDim.x, gy = gridDim.y;
  int lin = (blockIdx.z * gy + blockIdx.y) * gx + blockIdx.x;
  int nwg = gx * gy * gridDim.z;
  int cpx = nwg >> 3;
  int swz = (lin & 7) * cpx + (lin >> 3);
  int bz = swz / (gx * gy);
  int rem = swz - bz * (gx * gy);
  int by = rem / gx, bx = rem - by * gx;

  int zj = bz / zdiv, zi = bz - zj * zdiv;
  A += (size_t)zj * sAmaj + (size_t)zi * sAmin;
  const ushort* bfb = Bf + (size_t)zj * sBmaj + (size_t)zi * sBmin;
  long long coff = (long long)zj * sCmaj + (long long)zi * sCmin;

  int m0 = by * 128, n0 = bx * 128;

  __shared__ __align__(16) ushort smem[16384];   // 32KB: 2 bufs x {Ah 8K, Al 8K}

  int t = threadIdx.x;
  int l = t & 63, w = t >> 6;
  int wm = w >> 1, wn = w & 1;

  f32x4 acc[4][4];
#pragma unroll
  for (int i = 0; i < 4; ++i)
#pragma unroll
    for (int j = 0; j < 4; ++j) acc[i][j] = (f32x4){0.f, 0.f, 0.f, 0.f};

  // A staging: thread covers row srow, int4-slots {sc,sc+1} of 4
  int srow = t >> 1;
  int sc = (t & 1) * 2;
  const ushort* gAh = A + (size_t)(m0 + srow) * lda + aHi + sc * 8;
  const ushort* gAl = A + (size_t)(m0 + srow) * lda + aLo + sc * 8;
  int wsw = ((srow >> 1) & 7) << 4;
  int wo0 = (srow * 64 + sc * 16) ^ wsw;
  int wo1 = wo0 ^ 16;

  // A fragment read offsets
  int aoff[4];
#pragma unroll
  for (int mi = 0; mi < 4; ++mi) {
    int row = wm * 64 + mi * 16 + (l & 15);
    aoff[mi] = (row * 64 + (l >> 4) * 16) ^ (((row >> 1) & 7) << 4);
  }

  // B frag pointers (per ni, hi and lo)
  const ushort* bph[4];
  const ushort* bpl[4];
  int ntg0 = (n0 >> 4) + wn * 4;
#pragma unroll
  for (int ni = 0; ni < 4; ++ni) {
    bph[ni] = bfb + ((size_t)(ntg0 + ni) * BKC) * 512 + l * 8;
    bpl[ni] = bfb + ((size_t)(BNT + ntg0 + ni) * BKC) * 512 + l * 8;
  }

  int4 a0h0, a0h1, a0l0, a0l1, a1h0, a1h1, a1l0, a1l1;
  short8v B0h[4], B0l[4], B1h[4], B1l[4];

#define LOADA0(s) { a0h0 = *(const int4*)(gAh + (s)*32); a0h1 = *(const int4*)(gAh + (s)*32 + 8); \
                    a0l0 = *(const int4*)(gAl + (s)*32); a0l1 = *(const int4*)(gAl + (s)*32 + 8); }
#define LOADA1(s) { a1h0 = *(const int4*)(gAh + (s)*32); a1h1 = *(const int4*)(gAh + (s)*32 + 8); \
                    a1l0 = *(const int4*)(gAl + (s)*32); a1l1 = *(const int4*)(gAl + (s)*32 + 8); }
#define STOREA(h0, h1, l0, l1, base) { char* nb = (char*)smem + (base); \
    *(int4*)(nb + wo0) = h0; *(int4*)(nb + wo1) = h1; \
    *(int4*)(nb + 8192 + wo0) = l0; *(int4*)(nb + 8192 + wo1) = l1; }
#define LOADB(BH, BL, s) { _Pragma("unroll") \
    for (int ni = 0; ni < 4; ++ni) { \
      BH[ni] = *(const short8v*)(bph[ni] + (size_t)(s) * 512); \
      BL[ni] = *(const short8v*)(bpl[ni] + (size_t)(s) * 512); } }
#define MFMA_STEP(ahb, alb, BH, BL) { \
    short8v ah[4], al[4]; \
    _Pragma("unroll") for (int mi = 0; mi < 4; ++mi) \
      ah[mi] = *(const short8v*)((char*)smem + (ahb) + aoff[mi]); \
    _Pragma("unroll") for (int mi = 0; mi < 4; ++mi) \
      al[mi] = *(const short8v*)((char*)smem + (alb) + aoff[mi]); \
    _Pragma("unroll") for (int ni = 0; ni < 4; ++ni) \
      _Pragma("unroll") for (int mi = 0; mi < 4; ++mi) \
        acc[mi][ni] = __builtin_amdgcn_mfma_f32_16x16x32_bf16(ah[mi], BH[ni], acc[mi][ni], 0, 0, 0); \
    _Pragma("unroll") for (int ni = 0; ni < 4; ++ni) \
      _Pragma("unroll") for (int mi = 0; mi < 4; ++mi) \
        acc[mi][ni] = __builtin_amdgcn_mfma_f32_16x16x32_bf16(al[mi], BH[ni], acc[mi][ni], 0, 0, 0); \
    _Pragma("unroll") for (int ni = 0; ni < 4; ++ni) \
      _Pragma("unroll") for (int mi = 0; mi < 4; ++mi) \
        acc[mi][ni] = __builtin_amdgcn_mfma_f32_16x16x32_bf16(ah[mi], BL[ni], acc[mi][ni], 0, 0, 0); }

  int nt = Kd >> 5;            // always even (>=4)
  LOADA0(0); LOADB(B0h, B0l, 0);
  LOADA1(1); LOADB(B1h, B1l, 1);
  STOREA(a0h0, a0h1, a0l0, a0l1, 0);
  __syncthreads();
  for (int s2 = 0; s2 < nt; s2 += 2) {
    if (s2 + 2 < nt) LOADA0(s2 + 2);
    MFMA_STEP(0, 8192, B0h, B0l);
    if (s2 + 2 < nt) LOADB(B0h, B0l, s2 + 2);
    STOREA(a1h0, a1h1, a1l0, a1l1, 16384);
    __syncthreads();
    if (s2 + 3 < nt) LOADA1(s2 + 3);
    MFMA_STEP(16384, 24576, B1h, B1l);
    if (s2 + 3 < nt) LOADB(B1h, B1l, s2 + 3);
    if (s2 + 2 < nt) STOREA(a0h0, a0h1, a0l0, a0l1, 0);
    __syncthreads();
  }
#undef LOADA0
#undef LOADA1
#undef STOREA
#undef LOADB
#undef MFMA_STEP

  // fold alpha + biases + relu into acc
#pragma unroll
  for (int mi = 0; mi < 4; ++mi)
#pragma unroll
    for (int j = 0; j < 4; ++j) {
      int m = m0 + wm * 64 + mi * 16 + (l >> 4) * 4 + j;
#pragma unroll
      for (int ni = 0; ni < 4; ++ni) {
        int n = n0 + wn * 64 + ni * 16 + (l & 15);
        float x = acc[mi][ni][j] * alpha;
        if (HAS_BN) x += bN[n];
        if (HAS_BSN) x += bSN[(size_t)(m % smod) * ldbs + n];
        if (RELU) x = fmaxf(x, 0.f);
        acc[mi][ni][j] = x;
      }
    }

  if (EPI == 0) {
    // fp32 LDS-bounce: two 64-row passes, coalesced int4 stores
    float* Fs = (float*)smem;
#pragma unroll
    for (int p = 0; p < 2; ++p) {
      __syncthreads();
      if (wm == p) {
#pragma unroll
        for (int mi = 0; mi < 4; ++mi)
#pragma unroll
          for (int j = 0; j < 4; ++j) {
            int r = mi * 16 + (l >> 4) * 4 + j;
#pragma unroll
            for (int ni = 0; ni < 4; ++ni) {
              int c = wn * 64 + ni * 16 + (l & 15);
              *(float*)((char*)Fs + ((r * 512 + c * 4) ^ ((r & 7) << 4))) = acc[mi][ni][j];
            }
          }
      }
      __syncthreads();
#pragma unroll
      for (int r8 = 0; r8 < 8; ++r8) {
        int idx = r8 * 256 + t;
        int row = idx >> 5, slot = idx & 31;
        int4 v = *(const int4*)((char*)Fs + ((row * 512 + slot * 16) ^ ((row & 7) << 4)));
        *(int4*)(Cf + coff + (size_t)(m0 + p * 64 + row) * ldc + n0 + slot * 4) = v;
      }
    }
  } else {
    __syncthreads();
    ushort* Es = smem;                     // [128][128] ushort = 32KB
    bool isQ = (EPI == 1) || (n0 < 1024);
    bool isK = (EPI == 2) && !isQ && (n0 < 2048);
    int bb = m0 >> 9, s0 = m0 & 511;
    int hh2 = isK ? ((n0 - 1024) >> 7) : ((n0 - 2048) >> 7);
    size_t kvb = (size_t)(bb * 8 + hh2) * 131072;
#pragma unroll
    for (int pass = 0; pass < 2; ++pass) {
      if (!(EPI == 2 && !isQ && !isK)) {
#pragma unroll
        for (int mi = 0; mi < 4; ++mi)
#pragma unroll
          for (int j = 0; j < 4; ++j) {
            int lr = wm * 64 + mi * 16 + (l >> 4) * 4 + j;
#pragma unroll
            for (int ni = 0; ni < 4; ++ni) {
              int lcb = (wn * 64 + ni * 16 + (l & 15)) * 2;
              float x = acc[mi][ni][j];
              ushort h = f2bf(x);
              ushort vv = (pass == 0) ? h : f2bf(x - bf2f(h));
              *(ushort*)((char*)Es + ((lr * 256 + lcb) ^ ((lr & 7) << 4))) = vv;
            }
          }
      } else {
        // V: transposed (rows = n-local = d, cols = m-local = s)
#pragma unroll
        for (int mi = 0; mi < 4; ++mi)
#pragma unroll
          for (int j = 0; j < 4; ++j) {
            int cc = (wm * 64 + mi * 16 + (l >> 4) * 4 + j) * 2;
#pragma unroll
            for (int ni = 0; ni < 4; ++ni) {
              int rr = wn * 64 + ni * 16 + (l & 15);
              float x = acc[mi][ni][j];
              ushort h = f2bf(x);
              ushort vv = (pass == 0) ? h : f2bf(x - bf2f(h));
              *(ushort*)((char*)Es + ((rr * 256 + cc) ^ ((rr & 7) << 4))) = vv;
            }
          }
      }
      __syncthreads();
      if (isQ) {
        int off = (pass == 0) ? 0 : splitOff;
#pragma unroll
        for (int r = 0; r < 8; ++r) {
          int idx = r * 256 + t;
          int row = idx >> 4, cb = (idx & 15) * 16;
          int4 v = *(const int4*)((char*)Es + ((row * 256 + cb) ^ ((row & 7) << 4)));
          *(int4*)((char*)(Ch + coff + (size_t)(m0 + row) * ldc + off + n0) + cb) = v;
        }
      } else if (isK) {
#pragma unroll
        for (int sw = 0; sw < 8; ++sw) {
          int idx = sw * 256 + t;
          int f = idx >> 6, l2 = idx & 63;
          int st = f >> 2, dc = f & 3;
          int row = st * 16 + (l2 & 15);
          int colB = (dc * 32 + ((l2 >> 4) << 3)) * 2;
          short8v v = *(const short8v*)((char*)Es + ((row * 256 + colB) ^ ((row & 7) << 4)));
          *(short8v*)(pK + kvb + (size_t)((pass * 32 + (s0 >> 4) + st) * 4 + dc) * 512 + l2 * 8) = v;
        }
      } else {
#pragma unroll
        for (int sw = 0; sw < 8; ++sw) {
          int idx = sw * 256 + t;
          int f = idx >> 6, l2 = idx & 63;
          int dt = f >> 2, sch = f & 3;
          int row = dt * 16 + (l2 & 15);
          int colB = (sch * 32 + ((l2 >> 4) << 3)) * 2;
          short8v v = *(const short8v*)((char*)Es + ((row * 256 + colB) ^ ((row & 7) << 4)));
          *(short8v*)(pV + kvb + (size_t)((pass * 8 + dt) * 16 + (s0 >> 5) + sch) * 512 + l2 * 8) = v;
        }
      }
      if (pass == 0) __syncthreads();
    }
  }
}

// ---------------- fused attention: QK^T -> softmax -> PV ----------------
// Block = 128 q rows x one (b,h). 512 thr, 8 waves (2 wm x 4 wn).
// Q staged once in LDS (4 d-subtiles, hi|lo). S strip 128x512 in regs (fp32).
// Full-row softmax (shfl within 16-lane col group + cross-wave via rowred).
// P split-bf16 staged per 128-col chunk into the same subtile format; PV
// consumes Vf frags. O epilogue = split row-major into attno.
__global__ __launch_bounds__(512, 2) void attn_k(
    const ushort* __restrict__ qbuf, const ushort* __restrict__ Kf,
    const ushort* __restrict__ Vf, ushort* __restrict__ attno)
{
  int qt = blockIdx.x;            // 0..3
  int bh = blockIdx.y;            // 0..63
  int b = bh >> 3, h = bh & 7;

  __shared__ __align__(16) ushort smem[32768];   // 64KB: hi [0,32K), lo [32K,64K)
  __shared__ float rowred[1024];                 // [max 0..511][sum 512..1023]

  int t = threadIdx.x;
  int l = t & 63, w = t >> 6;
  int wm = w >> 2, wn = w & 3;

  // ---- stage Q (hi|lo), 4 d-subtiles of [128][32] ----
  {
    int srow = t >> 2, sc = t & 3;
    const ushort* gQ = qbuf + (size_t)(b * 512 + qt * 128 + srow) * 2048 + h * 128 + sc * 8;
    int wo = (srow * 64 + sc * 16) ^ (((srow >> 1) & 7) << 4);
#pragma unroll
    for (int ks = 0; ks < 4; ++ks) {
      int4 vh = *(const int4*)(gQ + ks * 32);
      int4 vl = *(const int4*)(gQ + 1024 + ks * 32);
      *(int4*)((char*)smem + ks * 8192 + wo) = vh;
      *(int4*)((char*)smem + 32768 + ks * 8192 + wo) = vl;
    }
  }

  int aoff[4];
#pragma unroll
  for (int mi = 0; mi < 4; ++mi) {
    int row = wm * 64 + mi * 16 + (l & 15);
    aoff[mi] = (row * 64 + (l >> 4) * 16) ^ (((row >> 1) & 7) << 4);
  }

  __syncthreads();

  // ---- QK^T: S[c][mi][ni], c = 128-col chunk ----
  f32x4 S[4][4][2];
#pragma unroll
  for (int c = 0; c < 4; ++c)
#pragma unroll
    for (int mi = 0; mi < 4; ++mi)
#pragma unroll
      for (int ni = 0; ni < 2; ++ni) S[c][mi][ni] = (f32x4){0.f, 0.f, 0.f, 0.f};

  const ushort* Kb = Kf + (size_t)bh * 131072 + l * 8;
#pragma unroll
  for (int c = 0; c < 4; ++c) {
#pragma unroll
    for (int ks = 0; ks < 4; ++ks) {
      short8v bhf[2], blf[2], ahf[4], alf[4];
#pragma unroll
      for (int ni = 0; ni < 2; ++ni) {
        int ntk = c * 8 + wn * 2 + ni;
        bhf[ni] = *(const short8v*)(Kb + (size_t)(ntk * 4 + ks) * 512);
        blf[ni] = *(const short8v*)(Kb + (size_t)((32 + ntk) * 4 + ks) * 512);
      }
#pragma unroll
      for (int mi = 0; mi < 4; ++mi) {
        ahf[mi] = *(const short8v*)((char*)smem + ks * 8192 + aoff[mi]);
        alf[mi] = *(const short8v*)((char*)smem + 32768 + ks * 8192 + aoff[mi]);
      }
#pragma unroll
      for (int ni = 0; ni < 2; ++ni)
#pragma unroll
        for (int mi = 0; mi < 4; ++mi)
          S[c][mi][ni] = __builtin_amdgcn_mfma_f32_16x16x32_bf16(ahf[mi], bhf[ni], S[c][mi][ni], 0, 0, 0);
#pragma unroll
      for (int ni = 0; ni < 2; ++ni)
#pragma unroll
        for (int mi = 0; mi < 4; ++mi)
          S[c][mi][ni] = __builtin_amdgcn_mfma_f32_16x16x32_bf16(alf[mi], bhf[ni], S[c][mi][ni], 0, 0, 0);
#pragma unroll
      for (int ni = 0; ni < 2; ++ni)
#pragma unroll
        for (int mi = 0; mi < 4; ++mi)
          S[c][mi][ni] = __builtin_amdgcn_mfma_f32_16x16x32_bf16(ahf[mi], blf[ni], S[c][mi][ni], 0, 0, 0);
    }
  }

  // ---- full-row softmax (fp32) ----
  const float scale = 0.08838834764831845f;
  float inv16[4][4];
  {
    float mx[4][4];
#pragma unroll
    for (int mi = 0; mi < 4; ++mi)
#pragma unroll
      for (int j = 0; j < 4; ++j) {
        float m2 = -3.0e38f;
#pragma unroll
        for (int c = 0; c < 4; ++c)
#pragma unroll
          for (int ni = 0; ni < 2; ++ni) m2 = fmaxf(m2, S[c][mi][ni][j]);
#pragma unroll
        for (int off = 8; off; off >>= 1) m2 = fmaxf(m2, __shfl_xor(m2, off));
        mx[mi][j] = m2;
      }
    if ((l & 15) == 0) {
#pragma unroll
      for (int mi = 0; mi < 4; ++mi)
#pragma unroll
        for (int j = 0; j < 4; ++j) {
          int row = wm * 64 + mi * 16 + (l >> 4) * 4 + j;
          rowred[wn * 128 + row] = mx[mi][j];
        }
    }
    __syncthreads();
#pragma unroll
    for (int mi = 0; mi < 4; ++mi)
#pragma unroll
      for (int j = 0; j < 4; ++j) {
        int row = wm * 64 + mi * 16 + (l >> 4) * 4 + j;
        float m2 = fmaxf(fmaxf(rowred[row], rowred[128 + row]),
                         fmaxf(rowred[256 + row], rowred[384 + row]));
        mx[mi][j] = m2 * scale;
      }
    float sm[4][4];
#pragma unroll
    for (int mi = 0; mi < 4; ++mi)
#pragma unroll
      for (int j = 0; j < 4; ++j) {
        float s2 = 0.f;
#pragma unroll
        for (int c = 0; c < 4; ++c)
#pragma unroll
          for (int ni = 0; ni < 2; ++ni) {
            float p = __expf(fmaf(S[c][mi][ni][j], scale, -mx[mi][j]));
            S[c][mi][ni][j] = p;
            s2 += p;
          }
#pragma unroll
        for (int off = 8; off; off >>= 1) s2 += __shfl_xor(s2, off);
        sm[mi][j] = s2;
      }
    if ((l & 15) == 0) {
#pragma unroll
      for (int mi = 0; mi < 4; ++mi)
#pragma unroll
        for (int j = 0; j < 4; ++j) {
          int row = wm * 64 + mi * 16 + (l >> 4) * 4 + j;
          rowred[512 + wn * 128 + row] = sm[mi][j];
        }
    }
    __syncthreads();
#pragma unroll
    for (int mi = 0; mi < 4; ++mi)
#pragma unroll
      for (int j = 0; j < 4; ++j) {
        int row = wm * 64 + mi * 16 + (l >> 4) * 4 + j;
        float s2 = rowred[512 + row] + rowred[640 + row]
                 + rowred[768 + row] + rowred[896 + row];
        inv16[mi][j] = 1.f / s2;
      }
  }

  // ---- PV: per chunk, stage split P into LDS subtiles, MFMA with Vf ----
  f32x4 O[4][2];
#pragma unroll
  for (int mi = 0; mi < 4; ++mi)
#pragma unroll
    for (int ni = 0; ni < 2; ++ni) O[mi][ni] = (f32x4){0.f, 0.f, 0.f, 0.f};

  const ushort* Vb = Vf + (size_t)bh * 131072 + l * 8;
#pragma unroll
  for (int c = 0; c < 4; ++c) {
    __syncthreads();   // prior chunk's P reads (or Q reads) complete
#pragma unroll
    for (int mi = 0; mi < 4; ++mi)
#pragma unroll
      for (int j = 0; j < 4; ++j) {
        int row = wm * 64 + mi * 16 + (l >> 4) * 4 + j;
        int sw2 = ((row >> 1) & 7) << 4;
#pragma unroll
        for (int ni = 0; ni < 2; ++ni) {
          float p = S[c][mi][ni][j] * inv16[mi][j];
          ushort hh = f2bf(p);
          ushort ll2 = f2bf(p - bf2f(hh));
          int off = (row * 64 + (ni * 16 + (l & 15)) * 2) ^ sw2;
          *(ushort*)((char*)smem + wn * 8192 + off) = hh;
          *(ushort*)((char*)smem + 32768 + wn * 8192 + off) = ll2;
        }
      }
    __syncthreads();
#pragma unroll
    for (int ks = 0; ks < 4; ++ks) {
      short8v pah[4], pal[4], vbh[2], vbl[2];
#pragma unroll
      for (int ni = 0; ni < 2; ++ni) {
        int ntd = wn * 2 + ni;
        vbh[ni] = *(const short8v*)(Vb + (size_t)(ntd * 16 + c * 4 + ks) * 512);
        vbl[ni] = *(const short8v*)(Vb + (size_t)((8 + ntd) * 16 + c * 4 + ks) * 512);
      }
#pragma unroll
      for (int mi = 0; mi < 4; ++mi) {
        pah[mi] = *(const short8v*)((char*)smem + ks * 8192 + aoff[mi]);
        pal[mi] = *(const short8v*)((char*)smem + 32768 + ks * 8192 + aoff[mi]);
      }
#pragma unroll
      for (int ni = 0; ni < 2; ++ni)
#pragma unroll
        for (int mi = 0; mi < 4; ++mi)
          O[mi][ni] = __builtin_amdgcn_mfma_f32_16x16x32_bf16(pah[mi], vbh[ni], O[mi][ni], 0, 0, 0);
#pragma unroll
      for (int ni = 0; ni < 2; ++ni)
#pragma unroll
        for (int mi = 0; mi < 4; ++mi)
          O[mi][ni] = __builtin_amdgcn_mfma_f32_16x16x32_bf16(pal[mi], vbh[ni], O[mi][ni], 0, 0, 0);
#pragma unroll
      for (int ni = 0; ni < 2; ++ni)
#pragma unroll
        for (int mi = 0; mi < 4; ++mi)
          O[mi][ni] = __builtin_amdgcn_mfma_f32_16x16x32_bf16(pah[mi], vbl[ni], O[mi][ni], 0, 0, 0);
    }
  }

  // ---- O epilogue: split bf16 row-major into attno ----
  __syncthreads();
  ushort* Es = smem;
  size_t coff = (size_t)b * 1048576 + (size_t)h * 128;
  int m0 = qt * 128;
#pragma unroll
  for (int pass = 0; pass < 2; ++pass) {
#pragma unroll
    for (int mi = 0; mi < 4; ++mi)
#pragma unroll
      for (int j = 0; j < 4; ++j) {
        int lr = wm * 64 + mi * 16 + (l >> 4) * 4 + j;
#pragma unroll
        for (int ni = 0; ni < 2; ++ni) {
          int lcb = (wn * 32 + ni * 16 + (l & 15)) * 2;
          float x = O[mi][ni][j];
          ushort hh = f2bf(x);
          ushort vv = (pass == 0) ? hh : f2bf(x - bf2f(hh));
          *(ushort*)((char*)Es + ((lr * 256 + lcb) ^ ((lr & 7) << 4))) = vv;
        }
      }
    __syncthreads();
    int off = (pass == 0) ? 0 : 1024;
#pragma unroll
    for (int r = 0; r < 4; ++r) {
      int idx = r * 512 + t;
      int row = idx >> 4, cb = (idx & 15) * 16;
      int4 v = *(const int4*)((char*)Es + ((row * 256 + cb) ^ ((row & 7) << 4)));
      *(int4*)((char*)(attno + coff + (size_t)(m0 + row) * 2048 + off) + cb) = v;
    }
    if (pass == 0) __syncthreads();
  }
}

// ------- merged fp32 [N][K] -> frag-native hi|lo for all 5 weights -------
__global__ __launch_bounds__(64) void convall_k(
    const float* __restrict__ te_w1, const float* __restrict__ te_w2,
    const float* __restrict__ ain_w, const float* __restrict__ aout_w,
    const float* __restrict__ tr_w1, ushort* __restrict__ base)
{
  int kc = blockIdx.x, y = blockIdx.y, l = threadIdx.x;
  const float* W; int ldw, NT, nt2; ushort* dst;
  if (y < 64)       { W = te_w1;  ldw = 1026; NT = 64;  nt2 = y;       dst = base; }
  else if (y < 128) { W = te_w2;  ldw = 1024; NT = 64;  nt2 = y - 64;  dst = base + 2097152; }
  else if (y < 320) { W = ain_w;  ldw = 1024; NT = 192; nt2 = y - 128; dst = base + 4194304; }
  else if (y < 384) { W = aout_w; ldw = 1024; NT = 64;  nt2 = y - 320; dst = base + 10485760; }
  else              { W = tr_w1;  ldw = 1024; NT = 64;  nt2 = y - 384; dst = base + 12582912; }
  const float* src = W + (size_t)(nt2 * 16 + (l & 15)) * ldw + kc * 32 + ((l >> 4) << 3);
  ushort h8[8], l8[8];
#pragma unroll
  for (int j = 0; j < 8; ++j) {
    float x = src[j];
    h8[j] = f2bf(x);
    l8[j] = f2bf(x - bf2f(h8[j]));
  }
  *(int4*)(dst + ((size_t)nt2 * 32 + kc) * 512 + l * 8) = *(int4*)h8;
  *(int4*)(dst + ((size_t)(NT + nt2) * 32 + kc) * 512 + l * 8) = *(int4*)l8;
}

// ---------------- fp32 [N][K] -> bf16 hi|lo [N][2K] (row-major, for A) ----
__global__ __launch_bounds__(256) void convert_k(
    const float* __restrict__ W, int lda, ushort* __restrict__ Whl, int K)
{
  int r = blockIdx.x;
  int c = threadIdx.x * 4;
  const float* src = W + (size_t)r * lda + c;
  float x0 = src[0], x1 = src[1], x2 = src[2], x3 = src[3];
  ushort4 h, lo;
  h.x = f2bf(x0); lo.x = f2bf(x0 - bf2f(h.x));
  h.y = f2bf(x1); lo.y = f2bf(x1 - bf2f(h.y));
  h.z = f2bf(x2); lo.z = f2bf(x2 - bf2f(h.z));
  h.w = f2bf(x3); lo.w = f2bf(x3 - bf2f(h.w));
  ushort* dst = Whl + (size_t)r * 2 * K;
  *(ushort4*)&dst[c] = h;
  *(ushort4*)&dst[K + c] = lo;
}

// ---------------- seasonal / positional precompute (fp32) ----------------
__global__ __launch_bounds__(256) void precompute_k(
    const float* __restrict__ pos_emb,
    const float* __restrict__ se_w1, const float* __restrict__ se_b1,
    const float* __restrict__ se_w2, const float* __restrict__ se_b2,
    const float* __restrict__ sexp_w, const float* __restrict__ sexp_b,
    const float* __restrict__ te_w1, const float* __restrict__ te_b1,
    float* __restrict__ psea, float* __restrict__ bias1)
{
  int s = blockIdx.x, t = threadIdx.x;
  float ts = (float)s;
  float se = sinf(((ts * 2.0f) * 3.14159274101257324f) / 24.0f);
  __shared__ float l1[256], l2[256];
  l1[t] = fmaxf(se * se_w1[t] + se_b1[t], 0.f);
  __syncthreads();
  {
    float a = se_b2[t];
    const float* wr = se_w2 + (size_t)t * 256;
    for (int i = 0; i < 256; ++i) a += l1[i] * wr[i];
    l2[t] = a;
  }
  __syncthreads();
#pragma unroll
  for (int r = 0; r < 4; ++r) {
    int h = r * 256 + t;
    float v = sexp_b[h];
    const float* wr = sexp_w + (size_t)h * 256;
    for (int j = 0; j < 256; ++j) v += l2[j] * wr[j];
    psea[s * Hh + h] = pos_emb[s * Hh + h] + v;
    bias1[s * Hh + h] = te_b1[h] + ts * te_w1[(size_t)h * 1026 + 1024]
                                 + se * te_w1[(size_t)h * 1026 + 1025];
  }
}

// ---------------- logits = h1 @ tr_w2^T + b  (N=8, fp32 VALU) ----------
__global__ __launch_bounds__(256) void tr2_k(
    const float* __restrict__ h1, const float* __restrict__ w,
    const float* __restrict__ bias, float* __restrict__ logits)
{
  int wid = threadIdx.x >> 6, lane = threadIdx.x & 63;
  int t = blockIdx.x * 4 + wid;
  const float* x = h1 + (size_t)t * Hh;
  float acc[8];
#pragma unroll
  for (int e = 0; e < 8; ++e) acc[e] = 0.f;
  for (int k = lane; k < Hh; k += 64) {
    float xv = x[k];
#pragma unroll
    for (int e = 0; e < 8; ++e) acc[e] += xv * w[e * Hh + k];
  }
#pragma unroll
  for (int e = 0; e < 8; ++e) {
#pragma unroll
    for (int off = 32; off; off >>= 1) acc[e] += __shfl_xor(acc[e], off);
  }
  if (lane == 0) {
#pragma unroll
    for (int e = 0; e < 8; ++e) logits[(size_t)t * 8 + e] = acc[e] + bias[e];
  }
}

// ---------------- zero fill of dispatch+combine ----------------
__global__ __launch_bounds__(256) void fill0_k(float4* __restrict__ p, long long n4)
{
  long long i = (long long)blockIdx.x * 256 + threadIdx.x;
  long long stride = (long long)gridDim.x * 256;
  float4 z = make_float4(0.f, 0.f, 0.f, 0.f);
  for (; i < n4; i += stride) p[i] = z;
}

// ---------------- router: softmax, top2, slot writes, partial p-sums -------
__global__ __launch_bounds__(256) void router_k(
    float* __restrict__ out, float* __restrict__ partials)
{
  int t = blockIdx.x * 256 + threadIdx.x;            // token 0..4095
  float* lg = out + 100663296 + (size_t)t * 8;       // logits (in-place -> probs)
  float p[8];
#pragma unroll
  for (int e = 0; e < 8; ++e) p[e] = lg[e];
  float m = p[0];
#pragma unroll
  for (int e = 1; e < 8; ++e) m = fmaxf(m, p[e]);
  float s = 0.f;
#pragma unroll
  for (int e = 0; e < 8; ++e) { p[e] = expf(p[e] - m); s += p[e]; }
  float inv = 1.f / s;
#pragma unroll
  for (int e = 0; e < 8; ++e) p[e] *= inv;
#pragma unroll
  for (int e = 0; e < 8; ++e) lg[e] = p[e];          // router_probs out

  int i0 = 0; float v0 = p[0];
#pragma unroll
  for (int e = 1; e < 8; ++e) if (p[e] > v0) { v0 = p[e]; i0 = e; }
  int i1 = -1; float v1 = -1.f;
#pragma unroll
  for (int e = 0; e < 8; ++e) if (e != i0 && p[e] > v1) { v1 = p[e]; i1 = e; }
  float wn = 1.f / (v0 + v1);
  size_t db = (size_t)t * (8 * 1536);
  out[db + (size_t)i0 * 1536] = 1.f;
  out[db + (size_t)i1 * 1536] = 1.f;
  out[50331648 + db + (size_t)i0 * 1536] = v0 * wn;
  out[50331648 + db + (size_t)i1 * 1536] = v1 * wn;

  __shared__ float red[256];
#pragma unroll
  for (int e = 0; e < 8; ++e) {
    red[threadIdx.x] = p[e];
    __syncthreads();
    for (int st = 128; st; st >>= 1) {
      if (threadIdx.x < st) red[threadIdx.x] += red[threadIdx.x + st];
      __syncthreads();
    }
    if (threadIdx.x == 0) partials[blockIdx.x * 8 + e] = red[0];
    __syncthreads();
  }
}

// ---------------- aux loss + cleanup of partials scratch ----------------
__global__ __launch_bounds__(64) void aux_k(float* __restrict__ partials,
                                            float* __restrict__ out)
{
  int lane = threadIdx.x;
  float v = 0.f;
  if (lane < 8) {
    float s = 0.f;
    for (int b = 0; b < 16; ++b) s += partials[b * 8 + lane];
    float pm = s / 4096.f;
    v = pm * logf(pm * 8.f + 1e-9f);
  }
#pragma unroll
  for (int off = 4; off; off >>= 1) v += __shfl_xor(v, off);
  if (lane == 0) out[100696064] = v;
  partials[lane] = 0.f;
  partials[64 + lane] = 0.f;
}

extern "C" void kernel_launch(void* const* d_in, const int* in_sizes, int n_in,
                              void* d_out, int out_size, void* d_ws, size_t ws_size,
                              hipStream_t stream)
{
  const float* hidden = (const float*)d_in[0];
  const float* pos_emb = (const float*)d_in[1];
  const float* se_w1 = (const float*)d_in[2];
  const float* se_b1 = (const float*)d_in[3];
  const float* se_w2 = (const float*)d_in[4];
  const float* se_b2 = (const float*)d_in[5];
  const float* sexp_w = (const float*)d_in[6];
  const float* sexp_b = (const float*)d_in[7];
  const float* te_w1 = (const float*)d_in[8];
  const float* te_b1 = (const float*)d_in[9];
  const float* te_w2 = (const float*)d_in[10];
  const float* te_b2 = (const float*)d_in[11];
  const float* ain_w = (const float*)d_in[12];
  const float* ain_b = (const float*)d_in[13];
  const float* aout_w = (const float*)d_in[14];
  const float* aout_b = (const float*)d_in[15];
  const float* tr_w1 = (const float*)d_in[16];
  const float* tr_b1 = (const float*)d_in[17];
  const float* tr_w2 = (const float*)d_in[18];
  const float* tr_b2 = (const float*)d_in[19];
  float* out = (float*)d_out;

  // scratch arena: byte offsets inside d_out (402MB); fill0 re-zeroes all
  char* arena = (char*)d_out;
  ushort* Wbase= (ushort*)(arena + 0);          // W1f/W2f/Waf/Wof/Wtf 28MB
  ushort* hid2 = (ushort*)(arena + 29360128);   // [4096][2048] 16MB
  ushort* enc1 = (ushort*)(arena + 46137344);   // 16MB
  ushort* enc2 = (ushort*)(arena + 62914560);   // 16MB
  ushort* qbuf = (ushort*)(arena + 79691776);   // [4096][2048] 16MB
  ushort* Kf   = (ushort*)(arena + 96468992);   // [64][2][32][4][512] 16MB
  ushort* Vf   = (ushort*)(arena + 113246208);  // [64][2][8][16][512] 16MB
  ushort* attno= (ushort*)(arena + 197132288);  // 16MB
  ushort* encf = (ushort*)(arena + 213909504);  // 16MB
  float*  h1   = (float*)(arena + 230686720);   // [4096][1024] 16MB
  float*  psea = (float*)(arena + 247463936);   // 2MB
  float*  bias1= (float*)(arena + 249561088);   // 2MB
  float*  parts= out + 51380224;                // [16][8], zeroed by aux_k
  float*  lgts = out + 100663296;               // logits -> probs region

  convall_k<<<dim3(32, 448), 64, 0, stream>>>(te_w1, te_w2, ain_w, aout_w, tr_w1, Wbase);
  convert_k<<<4096, 256, 0, stream>>>(hidden, 1024, hid2, 1024);
  precompute_k<<<512, 256, 0, stream>>>(pos_emb, se_w1, se_b1, se_w2, se_b2,
                                        sexp_w, sexp_b, te_w1, te_b1, psea, bias1);

  // G1: enc1 = relu(hidden @ te_w1'^T + bias1[s])
  mgemm_k<1, true, false, true><<<dim3(8, 32, 1), 256, 0, stream>>>(
      hid2, 2048, 0, 0, 0, 1024,
      Wbase, 64, 32, 0, 0,
      nullptr, enc1, 2048, 0, 0, 1024, nullptr, nullptr,
      1024, 1, nullptr, bias1, 1024, 512, 1.f);

  // G2: enc2 = enc1 @ te_w2^T + te_b2 + psea[s]
  mgemm_k<1, false, true, true><<<dim3(8, 32, 1), 256, 0, stream>>>(
      enc1, 2048, 0, 0, 0, 1024,
      Wbase + 2097152, 64, 32, 0, 0,
      nullptr, enc2, 2048, 0, 0, 1024, nullptr, nullptr,
      1024, 1, te_b2, psea, 1024, 512, 1.f);

  // G3: qkv = enc2 @ attn_in_w^T + attn_in_b; Q row-major, K/V frag-native
  mgemm_k<2, false, true, false><<<dim3(24, 32, 1), 256, 0, stream>>>(
      enc2, 2048, 0, 0, 0, 1024,
      Wbase + 4194304, 192, 32, 0, 0,
      nullptr, qbuf, 2048, 0, 0, 1024, Kf, Vf,
      1024, 1, ain_b, nullptr, 1, 1, 1.f);

  // fused attention: QK^T -> softmax -> PV
  attn_k<<<dim3(4, 64), 512, 0, stream>>>(qbuf, Kf, Vf, attno);

  // G6: encf = attno @ attn_out_w^T + attn_out_b
  mgemm_k<1, false, true, false><<<dim3(8, 32, 1), 256, 0, stream>>>(
      attno, 2048, 0, 0, 0, 1024,
      Wbase + 10485760, 64, 32, 0, 0,
      nullptr, encf, 2048, 0, 0, 1024, nullptr, nullptr,
      1024, 1, aout_b, nullptr, 1, 1, 1.f);

  // G7: h1 = relu(encf @ tr_w1^T + tr_b1)  (fp32 out)
  mgemm_k<0, true, true, false><<<dim3(8, 32, 1), 256, 0, stream>>>(
      encf, 2048, 0, 0, 0, 1024,
      Wbase + 12582912, 64, 32, 0, 0,
      h1, nullptr, 1024, 0, 0, 0, nullptr, nullptr,
      1024, 1, tr_b1, nullptr, 1, 1, 1.f);

  tr2_k<<<1024, 256, 0, stream>>>(h1, tr_w2, tr_b2, lgts);

  // zero dispatch+combine (wipes all arena scratch)
  fill0_k<<<4096, 256, 0, stream>>>((float4*)out, 25165824LL);

  router_k<<<16, 256, 0, stream>>>(out, parts);
  aux_k<<<1, 64, 0, stream>>>(parts, out);
}